// Round 2
// baseline (571.807 us; speedup 1.0000x reference)
//
#include <hip/hip_runtime.h>
#include <stdint.h>

typedef unsigned short u16;
typedef __attribute__((ext_vector_type(8))) short short8;
typedef __attribute__((ext_vector_type(4))) float floatx4;

#define S_LEN 2048
#define NQKV 3072

__device__ inline float bf2f(u16 u) {
  union { uint32_t u; float f; } v; v.u = ((uint32_t)u) << 16; return v.f;
}
__device__ inline u16 f2bf(float f) {
  union { float f; uint32_t u; } v; v.f = f;
  uint32_t r = v.u + 0x7fffu + ((v.u >> 16) & 1u);
  return (u16)(r >> 16);
}
__device__ inline void gl2lds16(const u16* g, u16* l) {
  __builtin_amdgcn_global_load_lds((const __attribute__((address_space(1))) uint32_t*)g,
                                   (__attribute__((address_space(3))) uint32_t*)l, 16, 0, 0);
}

// ---------------- cast fp32 -> bf16, 4 elems/thread ----------------
__global__ void cast_k(const float* __restrict__ in, u16* __restrict__ out, int n4) {
  int i = blockIdx.x * 256 + threadIdx.x;
  if (i >= n4) return;
  float4 v = ((const float4*)in)[i];
  ushort4 o;
  o.x = f2bf(v.x); o.y = f2bf(v.y); o.z = f2bf(v.z); o.w = f2bf(v.w);
  ((ushort4*)out)[i] = o;
}

// ---------------- transpose+cast: in fp32 [K][N] -> out bf16 [N][K] ----------------
__global__ void transpose_k(const float* __restrict__ in, u16* __restrict__ out, int K, int N) {
  __shared__ u16 tile[32][33];
  int n0 = blockIdx.x * 32, k0 = blockIdx.y * 32;
  int tx = threadIdx.x, ty = threadIdx.y;  // 32 x 8
#pragma unroll
  for (int i = 0; i < 4; i++)
    tile[ty + 8 * i][tx] = f2bf(in[(size_t)(k0 + ty + 8 * i) * N + n0 + tx]);
  __syncthreads();
#pragma unroll
  for (int i = 0; i < 4; i++)
    out[(size_t)(n0 + ty + 8 * i) * K + k0 + tx] = tile[tx][ty + 8 * i];
}

// ---------------- GEMM: C[M][N] = A[M][K] * Bt[N][K]^T (bf16 in, fp32 acc) ----------------
template <bool OUTF32>
__global__ __launch_bounds__(256) void gemm_bt(const u16* __restrict__ A, const u16* __restrict__ Bt,
                                               void* __restrict__ Cv, int M, int N, int K) {
  __shared__ u16 As[128 * 32];  // [m][k], 8KB
  __shared__ u16 Bs[128 * 32];  // [n][k], 8KB
  const int m0 = blockIdx.y * 128, n0 = blockIdx.x * 128;
  const int t = threadIdx.x, w = t >> 6, lane = t & 63;
  const int quad = lane >> 4, l16 = lane & 15;
  const int wm = (w >> 1) * 64, wn = (w & 1) * 64;
  const int lrow = lane >> 2, lk = (lane & 3) * 8;
  floatx4 acc[4][4] = {};
  for (int k0 = 0; k0 < K; k0 += 32) {
#pragma unroll
    for (int c = 2 * w; c <= 2 * w + 1; ++c) {
      int row = c * 16 + lrow;
      gl2lds16(A + (size_t)(m0 + row) * K + k0 + lk, As + c * 512 + lane * 8);
      gl2lds16(Bt + (size_t)(n0 + row) * K + k0 + lk, Bs + c * 512 + lane * 8);
    }
    __syncthreads();
    short8 a[4], b[4];
#pragma unroll
    for (int mt = 0; mt < 4; mt++) a[mt] = *(const short8*)(As + (wm + mt * 16 + l16) * 32 + quad * 8);
#pragma unroll
    for (int nt = 0; nt < 4; nt++) b[nt] = *(const short8*)(Bs + (wn + nt * 16 + l16) * 32 + quad * 8);
#pragma unroll
    for (int mt = 0; mt < 4; mt++)
#pragma unroll
      for (int nt = 0; nt < 4; nt++)
        acc[mt][nt] = __builtin_amdgcn_mfma_f32_16x16x32_bf16(a[mt], b[nt], acc[mt][nt], 0, 0, 0);
    __syncthreads();
  }
#pragma unroll
  for (int mt = 0; mt < 4; mt++)
#pragma unroll
    for (int nt = 0; nt < 4; nt++)
#pragma unroll
      for (int r = 0; r < 4; r++) {
        int row = m0 + wm + mt * 16 + quad * 4 + r;
        int col = n0 + wn + nt * 16 + l16;
        if (OUTF32)
          ((float*)Cv)[(size_t)row * N + col] = acc[mt][nt][r];
        else
          ((u16*)Cv)[(size_t)row * N + col] = f2bf(acc[mt][nt][r]);
      }
}

// ---------------- RoPE in place on QKV buffer (bf16) ----------------
__global__ void rope_k(u16* __restrict__ qkv, const int* __restrict__ pos) {
  int idx = blockIdx.x * 256 + threadIdx.x;  // 4096*20*64 threads
  int i = idx & 63;
  int hh = (idx >> 6) % 20;      // 0..15 Q heads, 16..19 K heads
  int row = idx / (64 * 20);     // 0..4095
  int s = row & (S_LEN - 1);
  float p = (float)pos[s];
  float freq = __expf(-(float)i * 0.015625f * 9.210340371976184f);  // base^(-2i/128)
  float ang = p * freq;
  float c = cosf(ang), sn = sinf(ang);
  int col = (hh < 16) ? hh * 128 : 2048 + (hh - 16) * 128;
  size_t base = (size_t)row * NQKV + col + i;
  float t1 = bf2f(qkv[base]), t2 = bf2f(qkv[base + 64]);
  qkv[base] = f2bf(t1 * c - t2 * sn);
  qkv[base + 64] = f2bf(t2 * c + t1 * sn);
}

// ---------------- Flash attention, causal GQA ----------------
// grid: (S/128, NH, B), block 256 (4 waves, 32 q-rows each). BK=64 keys/iter.
#define KL_LD 136  // padded row stride (elems) for K tile [key][d]
#define VT_LD 72   // padded row stride for Vt [d][key]
#define PL_LD 72   // padded row stride for P [row][key]
__global__ __launch_bounds__(256) void attn_k(const u16* __restrict__ qkv, u16* __restrict__ ctx) {
  __shared__ u16 Kl[64 * KL_LD];
  __shared__ u16 Vt[128 * VT_LD];
  __shared__ u16 Pl[4][32 * PL_LD];
  const int q0 = blockIdx.x * 128;
  const int h = blockIdx.y;
  const int bb = blockIdx.z;
  const int kvh = h >> 2;
  const int t = threadIdx.x, w = t >> 6, lane = t & 63;
  const int quad = lane >> 4, l16 = lane & 15;
  const size_t rowbase = (size_t)bb * S_LEN;
  const int r0w = q0 + w * 32;

  short8 qf[2][4];
#pragma unroll
  for (int mt = 0; mt < 2; mt++)
#pragma unroll
    for (int ks = 0; ks < 4; ks++)
      qf[mt][ks] = *(const short8*)(qkv + (rowbase + r0w + mt * 16 + l16) * NQKV + h * 128 + ks * 32 + quad * 8);

  floatx4 acc[2][8] = {};
  float m_i[2][4], l_i[2][4];
#pragma unroll
  for (int mt = 0; mt < 2; mt++)
#pragma unroll
    for (int r = 0; r < 4; r++) { m_i[mt][r] = -1e30f; l_i[mt][r] = 0.f; }

  const int nkb = (q0 + 128) >> 6;
  for (int kb = 0; kb < nkb; kb++) {
    {  // stage K tile [64][128] and transposed V tile [128][64]
      const u16* Kg = qkv + (rowbase + kb * 64) * NQKV + 2048 + kvh * 128;
#pragma unroll
      for (int ii = 0; ii < 4; ii++) {
        int c = t + ii * 256;
        int key = c >> 4, dblk = c & 15;
        *(uint4*)(Kl + key * KL_LD + dblk * 8) = *(const uint4*)(Kg + (size_t)key * NQKV + dblk * 8);
      }
      const u16* Vg = qkv + (rowbase + kb * 64) * NQKV + 2560 + kvh * 128;
#pragma unroll
      for (int ii = 0; ii < 4; ii++) {
        int c = t + ii * 256;
        int key = c & 63, dblk = c >> 6;
        uint4 vv = *(const uint4*)(Vg + (size_t)key * NQKV + dblk * 8);
        const u16* tp = (const u16*)&vv;
#pragma unroll
        for (int j = 0; j < 8; j++) Vt[(dblk * 8 + j) * VT_LD + key] = tp[j];
      }
    }
    __syncthreads();
    if (kb * 64 <= r0w + 31) {  // wave-uniform participation
      floatx4 sc[2][4];
#pragma unroll
      for (int nt = 0; nt < 4; nt++) {
        short8 kf[4];
#pragma unroll
        for (int ks = 0; ks < 4; ks++) kf[ks] = *(const short8*)(Kl + (nt * 16 + l16) * KL_LD + ks * 32 + quad * 8);
#pragma unroll
        for (int mt = 0; mt < 2; mt++) {
          floatx4 s = {0.f, 0.f, 0.f, 0.f};
#pragma unroll
          for (int ks = 0; ks < 4; ks++) s = __builtin_amdgcn_mfma_f32_16x16x32_bf16(qf[mt][ks], kf[ks], s, 0, 0, 0);
          sc[mt][nt] = s;
        }
      }
      const bool need_mask = (kb * 64 + 63 > r0w);
      const float scale = 0.08838834764831845f;
#pragma unroll
      for (int mt = 0; mt < 2; mt++)
#pragma unroll
        for (int nt = 0; nt < 4; nt++)
#pragma unroll
          for (int r = 0; r < 4; r++) {
            float v = sc[mt][nt][r] * scale;
            if (need_mask) {
              int keyg = kb * 64 + nt * 16 + l16;
              int rowg = r0w + mt * 16 + quad * 4 + r;
              if (keyg > rowg) v = -1e30f;
            }
            sc[mt][nt][r] = v;
          }
#pragma unroll
      for (int mt = 0; mt < 2; mt++) {
        float alpha[4];
#pragma unroll
        for (int r = 0; r < 4; r++) {
          float rm = fmaxf(fmaxf(sc[mt][0][r], sc[mt][1][r]), fmaxf(sc[mt][2][r], sc[mt][3][r]));
#pragma unroll
          for (int off = 1; off < 16; off <<= 1) rm = fmaxf(rm, __shfl_xor(rm, off));
          float mn = fmaxf(m_i[mt][r], rm);
          alpha[r] = __expf(m_i[mt][r] - mn);
          m_i[mt][r] = mn;
          float rs = 0.f;
#pragma unroll
          for (int nt = 0; nt < 4; nt++) {
            float pv = __expf(sc[mt][nt][r] - mn);
            sc[mt][nt][r] = pv;
            rs += pv;
          }
#pragma unroll
          for (int off = 1; off < 16; off <<= 1) rs += __shfl_xor(rs, off);
          l_i[mt][r] = l_i[mt][r] * alpha[r] + rs;
        }
#pragma unroll
        for (int nto = 0; nto < 8; nto++)
#pragma unroll
          for (int r = 0; r < 4; r++) acc[mt][nto][r] *= alpha[r];
#pragma unroll
        for (int nt = 0; nt < 4; nt++)
#pragma unroll
          for (int r = 0; r < 4; r++)
            Pl[w][(mt * 16 + quad * 4 + r) * PL_LD + nt * 16 + l16] = f2bf(sc[mt][nt][r]);
      }
      // PV
      short8 pf[2][2];
#pragma unroll
      for (int mt = 0; mt < 2; mt++)
#pragma unroll
        for (int ks = 0; ks < 2; ks++)
          pf[mt][ks] = *(const short8*)(Pl[w] + (mt * 16 + l16) * PL_LD + ks * 32 + quad * 8);
#pragma unroll
      for (int nto = 0; nto < 8; nto++) {
        short8 vf0 = *(const short8*)(Vt + (nto * 16 + l16) * VT_LD + quad * 8);
        short8 vf1 = *(const short8*)(Vt + (nto * 16 + l16) * VT_LD + 32 + quad * 8);
#pragma unroll
        for (int mt = 0; mt < 2; mt++) {
          acc[mt][nto] = __builtin_amdgcn_mfma_f32_16x16x32_bf16(pf[mt][0], vf0, acc[mt][nto], 0, 0, 0);
          acc[mt][nto] = __builtin_amdgcn_mfma_f32_16x16x32_bf16(pf[mt][1], vf1, acc[mt][nto], 0, 0, 0);
        }
      }
    }
    __syncthreads();
  }
#pragma unroll
  for (int mt = 0; mt < 2; mt++)
#pragma unroll
    for (int nto = 0; nto < 8; nto++)
#pragma unroll
      for (int r = 0; r < 4; r++) {
        int rowg = r0w + mt * 16 + quad * 4 + r;
        int col = h * 128 + nto * 16 + l16;
        ctx[(rowbase + rowg) * 2048 + col] = f2bf(acc[mt][nto][r] / l_i[mt][r]);
      }
}

extern "C" void kernel_launch(void* const* d_in, const int* in_sizes, int n_in,
                              void* d_out, int out_size, void* d_ws, size_t ws_size,
                              hipStream_t stream) {
  const float* x  = (const float*)d_in[0];
  const int* pos  = (const int*)d_in[1];
  const float* Wq = (const float*)d_in[2];
  const float* Wk = (const float*)d_in[3];
  const float* Wv = (const float*)d_in[4];
  const float* Wo = (const float*)d_in[5];
  float* out = (float*)d_out;
  char* ws = (char*)d_ws;
  // ws layout (bf16): Xb[4096][2048] | WT[3072][2048] | WoT[2048][2048] | QKV[4096][3072] | CTX[4096][2048]
  u16* Xb  = (u16*)(ws);
  u16* WT  = (u16*)(ws + 16777216);
  u16* WoT = (u16*)(ws + 29360128);
  u16* QKV = (u16*)(ws + 37748736);
  u16* CTX = (u16*)(ws + 62914560);

  hipLaunchKernelGGL(cast_k, dim3(8192), dim3(256), 0, stream, x, Xb, 2097152);

  dim3 tb(32, 8);
  hipLaunchKernelGGL(transpose_k, dim3(64, 64), tb, 0, stream, Wq, WT, 2048, 2048);
  hipLaunchKernelGGL(transpose_k, dim3(16, 64), tb, 0, stream, Wk, WT + (size_t)2048 * 2048, 2048, 512);
  hipLaunchKernelGGL(transpose_k, dim3(16, 64), tb, 0, stream, Wv, WT + (size_t)2560 * 2048, 2048, 512);
  hipLaunchKernelGGL(transpose_k, dim3(64, 64), tb, 0, stream, Wo, WoT, 2048, 2048);

  hipLaunchKernelGGL(HIP_KERNEL_NAME(gemm_bt<false>), dim3(24, 32), dim3(256), 0, stream,
                     Xb, WT, (void*)QKV, 4096, 3072, 2048);
  hipLaunchKernelGGL(rope_k, dim3(20480), dim3(256), 0, stream, QKV, pos);
  hipLaunchKernelGGL(attn_k, dim3(16, 16, 2), dim3(256), 0, stream, QKV, CTX);
  hipLaunchKernelGGL(HIP_KERNEL_NAME(gemm_bt<true>), dim3(16, 32), dim3(256), 0, stream,
                     CTX, WoT, (void*)out, 4096, 2048, 2048);
}

// Round 3
// 498.291 us; speedup vs baseline: 1.1475x; 1.1475x over previous
//
#include <hip/hip_runtime.h>
#include <stdint.h>

typedef unsigned short u16;
typedef __attribute__((ext_vector_type(8))) short short8;
typedef __attribute__((ext_vector_type(4))) float floatx4;

#define S_LEN 2048
#define NQKV 3072

__device__ inline float bf2f(u16 u) {
  union { uint32_t u; float f; } v; v.u = ((uint32_t)u) << 16; return v.f;
}
__device__ inline u16 f2bf(float f) {
  union { float f; uint32_t u; } v; v.f = f;
  uint32_t r = v.u + 0x7fffu + ((v.u >> 16) & 1u);
  return (u16)(r >> 16);
}
__device__ inline void gl2lds16(const u16* g, u16* l) {
  __builtin_amdgcn_global_load_lds((const __attribute__((address_space(1))) uint32_t*)g,
                                   (__attribute__((address_space(3))) uint32_t*)l, 16, 0, 0);
}

// ---------------- cast fp32 -> bf16, 4 elems/thread ----------------
__global__ void cast_k(const float* __restrict__ in, u16* __restrict__ out, int n4) {
  int i = blockIdx.x * 256 + threadIdx.x;
  if (i >= n4) return;
  float4 v = ((const float4*)in)[i];
  ushort4 o;
  o.x = f2bf(v.x); o.y = f2bf(v.y); o.z = f2bf(v.z); o.w = f2bf(v.w);
  ((ushort4*)out)[i] = o;
}

// ---------------- transpose+cast: in fp32 [K][N] -> out bf16 [N][K] ----------------
__global__ void transpose_k(const float* __restrict__ in, u16* __restrict__ out, int K, int N) {
  __shared__ u16 tile[32][33];
  int n0 = blockIdx.x * 32, k0 = blockIdx.y * 32;
  int tx = threadIdx.x, ty = threadIdx.y;  // 32 x 8
#pragma unroll
  for (int i = 0; i < 4; i++)
    tile[ty + 8 * i][tx] = f2bf(in[(size_t)(k0 + ty + 8 * i) * N + n0 + tx]);
  __syncthreads();
#pragma unroll
  for (int i = 0; i < 4; i++)
    out[(size_t)(n0 + ty + 8 * i) * K + k0 + tx] = tile[tx][ty + 8 * i];
}

// ---------------- GEMM: C[M][N] = A[M][K] * Bt[N][K]^T (bf16 in, fp32 acc) ----------------
template <bool OUTF32>
__global__ __launch_bounds__(256) void gemm_bt(const u16* __restrict__ A, const u16* __restrict__ Bt,
                                               void* __restrict__ Cv, int M, int N, int K) {
  __shared__ u16 As[128 * 32];  // [m][k], 8KB
  __shared__ u16 Bs[128 * 32];  // [n][k], 8KB
  const int m0 = blockIdx.y * 128, n0 = blockIdx.x * 128;
  const int t = threadIdx.x, w = t >> 6, lane = t & 63;
  const int quad = lane >> 4, l16 = lane & 15;
  const int wm = (w >> 1) * 64, wn = (w & 1) * 64;
  const int lrow = lane >> 2, lk = (lane & 3) * 8;
  floatx4 acc[4][4] = {};
  for (int k0 = 0; k0 < K; k0 += 32) {
#pragma unroll
    for (int c = 2 * w; c <= 2 * w + 1; ++c) {
      int row = c * 16 + lrow;
      gl2lds16(A + (size_t)(m0 + row) * K + k0 + lk, As + c * 512 + lane * 8);
      gl2lds16(Bt + (size_t)(n0 + row) * K + k0 + lk, Bs + c * 512 + lane * 8);
    }
    __syncthreads();
    short8 a[4], b[4];
#pragma unroll
    for (int mt = 0; mt < 4; mt++) a[mt] = *(const short8*)(As + (wm + mt * 16 + l16) * 32 + quad * 8);
#pragma unroll
    for (int nt = 0; nt < 4; nt++) b[nt] = *(const short8*)(Bs + (wn + nt * 16 + l16) * 32 + quad * 8);
#pragma unroll
    for (int mt = 0; mt < 4; mt++)
#pragma unroll
      for (int nt = 0; nt < 4; nt++)
        acc[mt][nt] = __builtin_amdgcn_mfma_f32_16x16x32_bf16(a[mt], b[nt], acc[mt][nt], 0, 0, 0);
    __syncthreads();
  }
#pragma unroll
  for (int mt = 0; mt < 4; mt++)
#pragma unroll
    for (int nt = 0; nt < 4; nt++)
#pragma unroll
      for (int r = 0; r < 4; r++) {
        int row = m0 + wm + mt * 16 + quad * 4 + r;
        int col = n0 + wn + nt * 16 + l16;
        if (OUTF32)
          ((float*)Cv)[(size_t)row * N + col] = acc[mt][nt][r];
        else
          ((u16*)Cv)[(size_t)row * N + col] = f2bf(acc[mt][nt][r]);
      }
}

// ---------------- RoPE in place on QKV buffer (bf16) ----------------
__global__ void rope_k(u16* __restrict__ qkv, const int* __restrict__ pos) {
  int idx = blockIdx.x * 256 + threadIdx.x;  // 4096*20*64 threads
  int i = idx & 63;
  int hh = (idx >> 6) % 20;      // 0..15 Q heads, 16..19 K heads
  int row = idx / (64 * 20);     // 0..4095
  int s = row & (S_LEN - 1);
  float p = (float)pos[s];
  float freq = __expf(-(float)i * 0.015625f * 9.210340371976184f);  // base^(-2i/128)
  float ang = p * freq;
  float c = cosf(ang), sn = sinf(ang);
  int col = (hh < 16) ? hh * 128 : 2048 + (hh - 16) * 128;
  size_t base = (size_t)row * NQKV + col + i;
  float t1 = bf2f(qkv[base]), t2 = bf2f(qkv[base + 64]);
  qkv[base] = f2bf(t1 * c - t2 * sn);
  qkv[base + 64] = f2bf(t2 * c + t1 * sn);
}

// ---------------- Flash attention, causal GQA, pair-balanced ----------------
// grid: (16 pairs, NH, B), block 256 (4 waves x 16 q-rows per tile).
// Block p handles q-tiles {p, 31-p} (BQ=64); single k-loop over union range,
// K/V staged once and consumed by both tiles. Register-prefetch pipeline.
#define KL_LD 136  // padded row stride for K tile [key][d]
#define VT_LD 72   // padded row stride for Vt [d][key]
#define PL_LD 72   // padded row stride for P [row][key]
__global__ __launch_bounds__(256, 2) void attn_k(const u16* __restrict__ qkv, u16* __restrict__ ctx) {
  __shared__ u16 Kl[64 * KL_LD];        // 17408 B
  __shared__ u16 Vt[128 * VT_LD];       // 18432 B
  __shared__ u16 Pl[4][2][16 * PL_LD];  // 18432 B
  const int p = blockIdx.x;             // 0..15
  const int lo = p, hi = 31 - p;
  const int h = blockIdx.y, bb = blockIdx.z;
  const int kvh = h >> 2;
  const int t = threadIdx.x, w = t >> 6, lane = t & 63;
  const int quad = lane >> 4, l16 = lane & 15;
  const size_t rowbase = (size_t)bb * S_LEN;
  const int rt0 = lo * 64 + w * 16;
  const int rt1 = hi * 64 + w * 16;

  // Q fragments for both tiles
  short8 qf[2][4];
#pragma unroll
  for (int ks = 0; ks < 4; ks++) {
    qf[0][ks] = *(const short8*)(qkv + (rowbase + rt0 + l16) * NQKV + h * 128 + ks * 32 + quad * 8);
    qf[1][ks] = *(const short8*)(qkv + (rowbase + rt1 + l16) * NQKV + h * 128 + ks * 32 + quad * 8);
  }

  floatx4 acc[2][8] = {};
  float m_i[2][4], l_i[2][4];
#pragma unroll
  for (int ti = 0; ti < 2; ti++)
#pragma unroll
    for (int r = 0; r < 4; r++) { m_i[ti][r] = -1e30f; l_i[ti][r] = 0.f; }

  // staging offsets (per thread, constant across iters)
  int koff[4], klds[4], voff[4], vlds_key[4], vlds_d[4];
#pragma unroll
  for (int ii = 0; ii < 4; ii++) {
    int c = t + ii * 256;
    koff[ii] = (c >> 4) * NQKV + (c & 15) * 8;
    klds[ii] = (c >> 4) * KL_LD + (c & 15) * 8;
    voff[ii] = (c & 63) * NQKV + (c >> 6) * 8;
    vlds_key[ii] = c & 63;
    vlds_d[ii] = (c >> 6) * 8;
  }
  const u16* Kg0 = qkv + rowbase * NQKV + 2048 + kvh * 128;
  const u16* Vg0 = qkv + rowbase * NQKV + 2560 + kvh * 128;

  uint4 kr[4], vr[4];
#pragma unroll
  for (int ii = 0; ii < 4; ii++) {
    kr[ii] = *(const uint4*)(Kg0 + koff[ii]);
    vr[ii] = *(const uint4*)(Vg0 + voff[ii]);
  }

  const int nkb = hi + 1;
  for (int kb = 0; kb < nkb; kb++) {
    __syncthreads();  // previous iter's LDS reads complete
#pragma unroll
    for (int ii = 0; ii < 4; ii++) *(uint4*)(Kl + klds[ii]) = kr[ii];
#pragma unroll
    for (int ii = 0; ii < 4; ii++) {
      const u16* tp = (const u16*)&vr[ii];
#pragma unroll
      for (int j = 0; j < 8; j++) Vt[(vlds_d[ii] + j) * VT_LD + vlds_key[ii]] = tp[j];
    }
    __syncthreads();
    if (kb + 1 < nkb) {  // prefetch next K/V block into registers (overlaps compute)
      const u16* Kg = Kg0 + (size_t)(kb + 1) * 64 * NQKV;
      const u16* Vg = Vg0 + (size_t)(kb + 1) * 64 * NQKV;
#pragma unroll
      for (int ii = 0; ii < 4; ii++) kr[ii] = *(const uint4*)(Kg + koff[ii]);
#pragma unroll
      for (int ii = 0; ii < 4; ii++) vr[ii] = *(const uint4*)(Vg + voff[ii]);
    }

    const bool do0 = (kb <= lo);  // tile lo active?  tile hi always active (kb <= hi)
    // ---- QK^T for both tiles, sharing kf fragments ----
    floatx4 sc[2][4];
#pragma unroll
    for (int nt = 0; nt < 4; nt++) {
      short8 kf[4];
#pragma unroll
      for (int ks = 0; ks < 4; ks++) kf[ks] = *(const short8*)(Kl + (nt * 16 + l16) * KL_LD + ks * 32 + quad * 8);
      floatx4 s1 = {0.f, 0.f, 0.f, 0.f};
#pragma unroll
      for (int ks = 0; ks < 4; ks++) s1 = __builtin_amdgcn_mfma_f32_16x16x32_bf16(qf[1][ks], kf[ks], s1, 0, 0, 0);
      sc[1][nt] = s1;
      if (do0) {
        floatx4 s0 = {0.f, 0.f, 0.f, 0.f};
#pragma unroll
        for (int ks = 0; ks < 4; ks++) s0 = __builtin_amdgcn_mfma_f32_16x16x32_bf16(qf[0][ks], kf[ks], s0, 0, 0, 0);
        sc[0][nt] = s0;
      }
    }
    // ---- mask + online softmax + P store (per tile) ----
    const float scale = 0.08838834764831845f;
#pragma unroll
    for (int ti = 0; ti < 2; ti++) {
      if (ti == 0 && !do0) continue;
      const int rtw = (ti == 0) ? rt0 : rt1;
      const bool need_mask = (kb * 64 + 63 > rtw);
#pragma unroll
      for (int nt = 0; nt < 4; nt++)
#pragma unroll
        for (int r = 0; r < 4; r++) {
          float v = sc[ti][nt][r] * scale;
          if (need_mask) {
            int keyg = kb * 64 + nt * 16 + l16;
            int rowg = rtw + quad * 4 + r;
            if (keyg > rowg) v = -1e30f;
          }
          sc[ti][nt][r] = v;
        }
      float alpha[4];
#pragma unroll
      for (int r = 0; r < 4; r++) {
        float rm = fmaxf(fmaxf(sc[ti][0][r], sc[ti][1][r]), fmaxf(sc[ti][2][r], sc[ti][3][r]));
#pragma unroll
        for (int off = 1; off < 16; off <<= 1) rm = fmaxf(rm, __shfl_xor(rm, off));
        float mn = fmaxf(m_i[ti][r], rm);
        alpha[r] = __expf(m_i[ti][r] - mn);
        m_i[ti][r] = mn;
        float rs = 0.f;
#pragma unroll
        for (int nt = 0; nt < 4; nt++) {
          float pv = __expf(sc[ti][nt][r] - mn);
          sc[ti][nt][r] = pv;
          rs += pv;
        }
#pragma unroll
        for (int off = 1; off < 16; off <<= 1) rs += __shfl_xor(rs, off);
        l_i[ti][r] = l_i[ti][r] * alpha[r] + rs;
      }
#pragma unroll
      for (int nto = 0; nto < 8; nto++)
#pragma unroll
        for (int r = 0; r < 4; r++) acc[ti][nto][r] *= alpha[r];
#pragma unroll
      for (int nt = 0; nt < 4; nt++)
#pragma unroll
        for (int r = 0; r < 4; r++)
          Pl[w][ti][(quad * 4 + r) * PL_LD + nt * 16 + l16] = f2bf(sc[ti][nt][r]);
    }
    // ---- PV for both tiles, sharing vf fragments ----
    short8 pf[2][2];
#pragma unroll
    for (int ks = 0; ks < 2; ks++) {
      pf[1][ks] = *(const short8*)(&Pl[w][1][0] + l16 * PL_LD + ks * 32 + quad * 8);
      if (do0) pf[0][ks] = *(const short8*)(&Pl[w][0][0] + l16 * PL_LD + ks * 32 + quad * 8);
    }
#pragma unroll
    for (int nto = 0; nto < 8; nto++) {
      short8 vf0 = *(const short8*)(Vt + (nto * 16 + l16) * VT_LD + quad * 8);
      short8 vf1 = *(const short8*)(Vt + (nto * 16 + l16) * VT_LD + 32 + quad * 8);
      acc[1][nto] = __builtin_amdgcn_mfma_f32_16x16x32_bf16(pf[1][0], vf0, acc[1][nto], 0, 0, 0);
      acc[1][nto] = __builtin_amdgcn_mfma_f32_16x16x32_bf16(pf[1][1], vf1, acc[1][nto], 0, 0, 0);
      if (do0) {
        acc[0][nto] = __builtin_amdgcn_mfma_f32_16x16x32_bf16(pf[0][0], vf0, acc[0][nto], 0, 0, 0);
        acc[0][nto] = __builtin_amdgcn_mfma_f32_16x16x32_bf16(pf[0][1], vf1, acc[0][nto], 0, 0, 0);
      }
    }
  }
  // ---- epilogue: both tiles ----
#pragma unroll
  for (int ti = 0; ti < 2; ti++) {
    const int rtw = (ti == 0) ? rt0 : rt1;
#pragma unroll
    for (int nto = 0; nto < 8; nto++)
#pragma unroll
      for (int r = 0; r < 4; r++) {
        int rowg = rtw + quad * 4 + r;
        int col = h * 128 + nto * 16 + l16;
        ctx[(rowbase + rowg) * 2048 + col] = f2bf(acc[ti][nto][r] / l_i[ti][r]);
      }
  }
}

extern "C" void kernel_launch(void* const* d_in, const int* in_sizes, int n_in,
                              void* d_out, int out_size, void* d_ws, size_t ws_size,
                              hipStream_t stream) {
  const float* x  = (const float*)d_in[0];
  const int* pos  = (const int*)d_in[1];
  const float* Wq = (const float*)d_in[2];
  const float* Wk = (const float*)d_in[3];
  const float* Wv = (const float*)d_in[4];
  const float* Wo = (const float*)d_in[5];
  float* out = (float*)d_out;
  char* ws = (char*)d_ws;
  // ws layout (bf16): Xb[4096][2048] | WT[3072][2048] | WoT[2048][2048] | QKV[4096][3072] | CTX[4096][2048]
  u16* Xb  = (u16*)(ws);
  u16* WT  = (u16*)(ws + 16777216);
  u16* WoT = (u16*)(ws + 29360128);
  u16* QKV = (u16*)(ws + 37748736);
  u16* CTX = (u16*)(ws + 62914560);

  hipLaunchKernelGGL(cast_k, dim3(8192), dim3(256), 0, stream, x, Xb, 2097152);

  dim3 tb(32, 8);
  hipLaunchKernelGGL(transpose_k, dim3(64, 64), tb, 0, stream, Wq, WT, 2048, 2048);
  hipLaunchKernelGGL(transpose_k, dim3(16, 64), tb, 0, stream, Wk, WT + (size_t)2048 * 2048, 2048, 512);
  hipLaunchKernelGGL(transpose_k, dim3(16, 64), tb, 0, stream, Wv, WT + (size_t)2560 * 2048, 2048, 512);
  hipLaunchKernelGGL(transpose_k, dim3(64, 64), tb, 0, stream, Wo, WoT, 2048, 2048);

  hipLaunchKernelGGL(HIP_KERNEL_NAME(gemm_bt<false>), dim3(24, 32), dim3(256), 0, stream,
                     Xb, WT, (void*)QKV, 4096, 3072, 2048);
  hipLaunchKernelGGL(rope_k, dim3(20480), dim3(256), 0, stream, QKV, pos);
  hipLaunchKernelGGL(attn_k, dim3(16, 16, 2), dim3(256), 0, stream, QKV, CTX);
  hipLaunchKernelGGL(HIP_KERNEL_NAME(gemm_bt<true>), dim3(16, 32), dim3(256), 0, stream,
                     CTX, WoT, (void*)out, 4096, 2048, 2048);
}

// Round 4
// 452.930 us; speedup vs baseline: 1.2625x; 1.1002x over previous
//
#include <hip/hip_runtime.h>
#include <stdint.h>

typedef unsigned short u16;
typedef __attribute__((ext_vector_type(8))) short short8;
typedef __attribute__((ext_vector_type(4))) float floatx4;

#define S_LEN 2048
#define NQKV 3072

__device__ inline float bf2f(u16 u) {
  union { uint32_t u; float f; } v; v.u = ((uint32_t)u) << 16; return v.f;
}
__device__ inline u16 f2bf(float f) {
  union { float f; uint32_t u; } v; v.f = f;
  uint32_t r = v.u + 0x7fffu + ((v.u >> 16) & 1u);
  return (u16)(r >> 16);
}
__device__ inline void gl2lds16(const u16* g, u16* l) {
  __builtin_amdgcn_global_load_lds((const __attribute__((address_space(1))) uint32_t*)g,
                                   (__attribute__((address_space(3))) uint32_t*)l, 16, 0, 0);
}

// ---------------- cast fp32 -> bf16, 4 elems/thread ----------------
__global__ void cast_k(const float* __restrict__ in, u16* __restrict__ out, int n4) {
  int i = blockIdx.x * 256 + threadIdx.x;
  if (i >= n4) return;
  float4 v = ((const float4*)in)[i];
  ushort4 o;
  o.x = f2bf(v.x); o.y = f2bf(v.y); o.z = f2bf(v.z); o.w = f2bf(v.w);
  ((ushort4*)out)[i] = o;
}

// ---------------- transpose+cast: in fp32 [K][N] -> out bf16 [N][K] ----------------
__global__ void transpose_k(const float* __restrict__ in, u16* __restrict__ out, int K, int N) {
  __shared__ u16 tile[32][33];
  int n0 = blockIdx.x * 32, k0 = blockIdx.y * 32;
  int tx = threadIdx.x, ty = threadIdx.y;  // 32 x 8
#pragma unroll
  for (int i = 0; i < 4; i++)
    tile[ty + 8 * i][tx] = f2bf(in[(size_t)(k0 + ty + 8 * i) * N + n0 + tx]);
  __syncthreads();
#pragma unroll
  for (int i = 0; i < 4; i++)
    out[(size_t)(n0 + ty + 8 * i) * K + k0 + tx] = tile[tx][ty + 8 * i];
}

// ---------------- V transpose: qkv V region [key][d] -> vt [bz][d][key] (bf16) ----------------
// grid: (64 key-tiles, 4 d-tiles, B*NKV), block (32,8)
__global__ void vtrans_k(const u16* __restrict__ qkv, u16* __restrict__ vt) {
  __shared__ u16 tile[32][33];
  int bk = blockIdx.x * 32, bd = blockIdx.y * 32, bz = blockIdx.z;
  int bb = bz >> 2, kvh = bz & 3;
  const u16* src = qkv + ((size_t)bb * S_LEN) * NQKV + 2560 + kvh * 128;
  u16* dst = vt + (size_t)bz * 128 * 2048;
  int tx = threadIdx.x, ty = threadIdx.y;
#pragma unroll
  for (int i = 0; i < 4; i++)
    tile[ty + 8 * i][tx] = src[(size_t)(bk + ty + 8 * i) * NQKV + bd + tx];
  __syncthreads();
#pragma unroll
  for (int i = 0; i < 4; i++)
    dst[(size_t)(bd + ty + 8 * i) * 2048 + bk + tx] = tile[tx][ty + 8 * i];
}

// ---------------- GEMM: C[M][N] = A[M][K] * Bt[N][K]^T (bf16 in, fp32 acc) ----------------
template <bool OUTF32>
__global__ __launch_bounds__(256) void gemm_bt(const u16* __restrict__ A, const u16* __restrict__ Bt,
                                               void* __restrict__ Cv, int M, int N, int K) {
  __shared__ u16 As[128 * 32];  // [m][k], 8KB
  __shared__ u16 Bs[128 * 32];  // [n][k], 8KB
  const int m0 = blockIdx.y * 128, n0 = blockIdx.x * 128;
  const int t = threadIdx.x, w = t >> 6, lane = t & 63;
  const int quad = lane >> 4, l16 = lane & 15;
  const int wm = (w >> 1) * 64, wn = (w & 1) * 64;
  const int lrow = lane >> 2, lk = (lane & 3) * 8;
  floatx4 acc[4][4] = {};
  for (int k0 = 0; k0 < K; k0 += 32) {
#pragma unroll
    for (int c = 2 * w; c <= 2 * w + 1; ++c) {
      int row = c * 16 + lrow;
      gl2lds16(A + (size_t)(m0 + row) * K + k0 + lk, As + c * 512 + lane * 8);
      gl2lds16(Bt + (size_t)(n0 + row) * K + k0 + lk, Bs + c * 512 + lane * 8);
    }
    __syncthreads();
    short8 a[4], b[4];
#pragma unroll
    for (int mt = 0; mt < 4; mt++) a[mt] = *(const short8*)(As + (wm + mt * 16 + l16) * 32 + quad * 8);
#pragma unroll
    for (int nt = 0; nt < 4; nt++) b[nt] = *(const short8*)(Bs + (wn + nt * 16 + l16) * 32 + quad * 8);
#pragma unroll
    for (int mt = 0; mt < 4; mt++)
#pragma unroll
      for (int nt = 0; nt < 4; nt++)
        acc[mt][nt] = __builtin_amdgcn_mfma_f32_16x16x32_bf16(a[mt], b[nt], acc[mt][nt], 0, 0, 0);
    __syncthreads();
  }
#pragma unroll
  for (int mt = 0; mt < 4; mt++)
#pragma unroll
    for (int nt = 0; nt < 4; nt++)
#pragma unroll
      for (int r = 0; r < 4; r++) {
        int row = m0 + wm + mt * 16 + quad * 4 + r;
        int col = n0 + wn + nt * 16 + l16;
        if (OUTF32)
          ((float*)Cv)[(size_t)row * N + col] = acc[mt][nt][r];
        else
          ((u16*)Cv)[(size_t)row * N + col] = f2bf(acc[mt][nt][r]);
      }
}

// ---------------- RoPE in place on QKV buffer (bf16), Q + K heads only ----------------
__global__ void rope_k(u16* __restrict__ qkv, const int* __restrict__ pos) {
  int idx = blockIdx.x * 256 + threadIdx.x;
  int i = idx & 63;
  int hh = (idx >> 6) % 20;
  int row = idx / (64 * 20);
  int s = row & (S_LEN - 1);
  float p = (float)pos[s];
  float freq = __expf(-(float)i * 0.015625f * 9.210340371976184f);
  float ang = p * freq;
  float c = cosf(ang), sn = sinf(ang);
  int col = (hh < 16) ? hh * 128 : 2048 + (hh - 16) * 128;
  size_t base = (size_t)row * NQKV + col + i;
  float t1 = bf2f(qkv[base]), t2 = bf2f(qkv[base + 64]);
  qkv[base] = f2bf(t1 * c - t2 * sn);
  qkv[base + 64] = f2bf(t2 * c + t1 * sn);
}

// ---------------- Flash attention, causal GQA, pair-balanced, no spills ----------------
// grid: (16 pairs, NH, B), block 256 (4 waves x 16 q-rows per tile).
// Block p handles q-tiles {p, 31-p}; K/V staged once per k-block, shared by both tiles.
#define KL_LD 136  // K tile row stride (272B, 16B-aligned, 2-way bank alias = free)
#define VT_LD 72   // Vt row stride (144B, 16B-aligned, conflict-free)
#define PL_LD 72
__global__ __launch_bounds__(256, 2) void attn_k(const u16* __restrict__ qkv,
                                                 const u16* __restrict__ vt,
                                                 u16* __restrict__ ctx) {
  __shared__ u16 Kl[64 * KL_LD];        // 17408 B
  __shared__ u16 Vl[128 * VT_LD];       // 18432 B
  __shared__ u16 Pl[4][2][16 * PL_LD];  // 18432 B
  const int p = blockIdx.x;
  const int lo = p, hi = 31 - p;
  const int h = blockIdx.y, bb = blockIdx.z;
  const int kvh = h >> 2;
  const int t = threadIdx.x, w = t >> 6, lane = t & 63;
  const int quad = lane >> 4, l16 = lane & 15;
  const size_t rowbase = (size_t)bb * S_LEN;
  const int rt0 = lo * 64 + w * 16;
  const int rt1 = hi * 64 + w * 16;

  short8 qf[2][4];
#pragma unroll
  for (int ks = 0; ks < 4; ks++) {
    qf[0][ks] = *(const short8*)(qkv + (rowbase + rt0 + l16) * NQKV + h * 128 + ks * 32 + quad * 8);
    qf[1][ks] = *(const short8*)(qkv + (rowbase + rt1 + l16) * NQKV + h * 128 + ks * 32 + quad * 8);
  }

  floatx4 acc[2][8] = {};
  float m_i[2][4], l_i[2][4];
#pragma unroll
  for (int ti = 0; ti < 2; ti++)
#pragma unroll
    for (int r = 0; r < 4; r++) { m_i[ti][r] = -1e30f; l_i[ti][r] = 0.f; }

  // staging offsets: K: c -> (key=c>>4, col=(c&15)*8); Vt: c -> (d=c>>3, key=(c&7)*8)
  int koff[4], klds[4], voff[4], vlds[4];
#pragma unroll
  for (int ii = 0; ii < 4; ii++) {
    int c = t + ii * 256;
    koff[ii] = (c >> 4) * NQKV + (c & 15) * 8;
    klds[ii] = (c >> 4) * KL_LD + (c & 15) * 8;
    voff[ii] = (c >> 3) * 2048 + (c & 7) * 8;
    vlds[ii] = (c >> 3) * VT_LD + (c & 7) * 8;
  }
  const u16* Kg0 = qkv + rowbase * NQKV + 2048 + kvh * 128;
  const u16* Vg0 = vt + (size_t)(bb * 4 + kvh) * 128 * 2048;

  const int nkb = hi + 1;
  for (int kb = 0; kb < nkb; kb++) {
    // ---- stage K [64][128] and Vt [128][64] (transit regs are short-lived) ----
    const u16* Kg = Kg0 + (size_t)kb * 64 * NQKV;
    const u16* Vg = Vg0 + kb * 64;
    uint4 kr[4], vr[4];
#pragma unroll
    for (int ii = 0; ii < 4; ii++) kr[ii] = *(const uint4*)(Kg + koff[ii]);
#pragma unroll
    for (int ii = 0; ii < 4; ii++) vr[ii] = *(const uint4*)(Vg + voff[ii]);
    __syncthreads();  // prev iter's LDS reads complete
#pragma unroll
    for (int ii = 0; ii < 4; ii++) *(uint4*)(Kl + klds[ii]) = kr[ii];
#pragma unroll
    for (int ii = 0; ii < 4; ii++) *(uint4*)(Vl + vlds[ii]) = vr[ii];
    __syncthreads();

    const bool do0 = (kb <= lo);
    // ---- QK^T for both tiles, sharing kf fragments ----
    floatx4 sc[2][4];
#pragma unroll
    for (int nt = 0; nt < 4; nt++) {
      short8 kf[4];
#pragma unroll
      for (int ks = 0; ks < 4; ks++) kf[ks] = *(const short8*)(Kl + (nt * 16 + l16) * KL_LD + ks * 32 + quad * 8);
      floatx4 s1 = {0.f, 0.f, 0.f, 0.f};
#pragma unroll
      for (int ks = 0; ks < 4; ks++) s1 = __builtin_amdgcn_mfma_f32_16x16x32_bf16(qf[1][ks], kf[ks], s1, 0, 0, 0);
      sc[1][nt] = s1;
      if (do0) {
        floatx4 s0 = {0.f, 0.f, 0.f, 0.f};
#pragma unroll
        for (int ks = 0; ks < 4; ks++) s0 = __builtin_amdgcn_mfma_f32_16x16x32_bf16(qf[0][ks], kf[ks], s0, 0, 0, 0);
        sc[0][nt] = s0;
      }
    }
    // ---- mask + online softmax + P store (per tile) ----
    const float scale = 0.08838834764831845f;
#pragma unroll
    for (int ti = 0; ti < 2; ti++) {
      if (ti == 0 && !do0) continue;
      const int rtw = (ti == 0) ? rt0 : rt1;
      const bool need_mask = (kb * 64 + 63 > rtw);
#pragma unroll
      for (int nt = 0; nt < 4; nt++)
#pragma unroll
        for (int r = 0; r < 4; r++) {
          float v = sc[ti][nt][r] * scale;
          if (need_mask) {
            int keyg = kb * 64 + nt * 16 + l16;
            int rowg = rtw + quad * 4 + r;
            if (keyg > rowg) v = -1e30f;
          }
          sc[ti][nt][r] = v;
        }
      float alpha[4];
#pragma unroll
      for (int r = 0; r < 4; r++) {
        float rm = fmaxf(fmaxf(sc[ti][0][r], sc[ti][1][r]), fmaxf(sc[ti][2][r], sc[ti][3][r]));
#pragma unroll
        for (int off = 1; off < 16; off <<= 1) rm = fmaxf(rm, __shfl_xor(rm, off));
        float mn = fmaxf(m_i[ti][r], rm);
        alpha[r] = __expf(m_i[ti][r] - mn);
        m_i[ti][r] = mn;
        float rs = 0.f;
#pragma unroll
        for (int nt = 0; nt < 4; nt++) {
          float pv = __expf(sc[ti][nt][r] - mn);
          sc[ti][nt][r] = pv;
          rs += pv;
        }
#pragma unroll
        for (int off = 1; off < 16; off <<= 1) rs += __shfl_xor(rs, off);
        l_i[ti][r] = l_i[ti][r] * alpha[r] + rs;
      }
#pragma unroll
      for (int nto = 0; nto < 8; nto++)
#pragma unroll
        for (int r = 0; r < 4; r++) acc[ti][nto][r] *= alpha[r];
#pragma unroll
      for (int nt = 0; nt < 4; nt++)
#pragma unroll
        for (int r = 0; r < 4; r++)
          Pl[w][ti][(quad * 4 + r) * PL_LD + nt * 16 + l16] = f2bf(sc[ti][nt][r]);
    }
    // ---- PV for both tiles, sharing vf fragments ----
    short8 pf[2][2];
#pragma unroll
    for (int ks = 0; ks < 2; ks++) {
      pf[1][ks] = *(const short8*)(&Pl[w][1][0] + l16 * PL_LD + ks * 32 + quad * 8);
      if (do0) pf[0][ks] = *(const short8*)(&Pl[w][0][0] + l16 * PL_LD + ks * 32 + quad * 8);
    }
#pragma unroll
    for (int nto = 0; nto < 8; nto++) {
      short8 vf0 = *(const short8*)(Vl + (nto * 16 + l16) * VT_LD + quad * 8);
      short8 vf1 = *(const short8*)(Vl + (nto * 16 + l16) * VT_LD + 32 + quad * 8);
      acc[1][nto] = __builtin_amdgcn_mfma_f32_16x16x32_bf16(pf[1][0], vf0, acc[1][nto], 0, 0, 0);
      acc[1][nto] = __builtin_amdgcn_mfma_f32_16x16x32_bf16(pf[1][1], vf1, acc[1][nto], 0, 0, 0);
      if (do0) {
        acc[0][nto] = __builtin_amdgcn_mfma_f32_16x16x32_bf16(pf[0][0], vf0, acc[0][nto], 0, 0, 0);
        acc[0][nto] = __builtin_amdgcn_mfma_f32_16x16x32_bf16(pf[0][1], vf1, acc[0][nto], 0, 0, 0);
      }
    }
  }
  // ---- epilogue ----
#pragma unroll
  for (int ti = 0; ti < 2; ti++) {
    const int rtw = (ti == 0) ? rt0 : rt1;
#pragma unroll
    for (int nto = 0; nto < 8; nto++)
#pragma unroll
      for (int r = 0; r < 4; r++) {
        int rowg = rtw + quad * 4 + r;
        int col = h * 128 + nto * 16 + l16;
        ctx[(rowbase + rowg) * 2048 + col] = f2bf(acc[ti][nto][r] / l_i[ti][r]);
      }
  }
}

extern "C" void kernel_launch(void* const* d_in, const int* in_sizes, int n_in,
                              void* d_out, int out_size, void* d_ws, size_t ws_size,
                              hipStream_t stream) {
  const float* x  = (const float*)d_in[0];
  const int* pos  = (const int*)d_in[1];
  const float* Wq = (const float*)d_in[2];
  const float* Wk = (const float*)d_in[3];
  const float* Wv = (const float*)d_in[4];
  const float* Wo = (const float*)d_in[5];
  float* out = (float*)d_out;
  char* ws = (char*)d_ws;
  // ws layout (bf16): Xb[4096][2048] | WT[3072][2048] | WoT[2048][2048] | QKV[4096][3072] | CTX[4096][2048]
  // Xb is dead after gemm1 -> reuse its space for VT (4 MB).
  u16* Xb  = (u16*)(ws);
  u16* WT  = (u16*)(ws + 16777216);
  u16* WoT = (u16*)(ws + 29360128);
  u16* QKV = (u16*)(ws + 37748736);
  u16* CTX = (u16*)(ws + 62914560);
  u16* VT  = Xb;  // [B*NKV][128][2048] bf16, 4 MB, reuses Xb after gemm1

  hipLaunchKernelGGL(cast_k, dim3(8192), dim3(256), 0, stream, x, Xb, 2097152);

  dim3 tb(32, 8);
  hipLaunchKernelGGL(transpose_k, dim3(64, 64), tb, 0, stream, Wq, WT, 2048, 2048);
  hipLaunchKernelGGL(transpose_k, dim3(16, 64), tb, 0, stream, Wk, WT + (size_t)2048 * 2048, 2048, 512);
  hipLaunchKernelGGL(transpose_k, dim3(16, 64), tb, 0, stream, Wv, WT + (size_t)2560 * 2048, 2048, 512);
  hipLaunchKernelGGL(transpose_k, dim3(64, 64), tb, 0, stream, Wo, WoT, 2048, 2048);

  hipLaunchKernelGGL(HIP_KERNEL_NAME(gemm_bt<false>), dim3(24, 32), dim3(256), 0, stream,
                     Xb, WT, (void*)QKV, 4096, 3072, 2048);
  hipLaunchKernelGGL(rope_k, dim3(20480), dim3(256), 0, stream, QKV, pos);
  hipLaunchKernelGGL(vtrans_k, dim3(64, 4, 8), tb, 0, stream, QKV, VT);
  hipLaunchKernelGGL(attn_k, dim3(16, 16, 2), dim3(256), 0, stream, QKV, VT, CTX);
  hipLaunchKernelGGL(HIP_KERNEL_NAME(gemm_bt<true>), dim3(16, 32), dim3(256), 0, stream,
                     CTX, WoT, (void*)out, 4096, 2048, 2048);
}